// Round 2
// baseline (46.611 us; speedup 1.0000x reference)
//
#include <hip/hip_runtime.h>
#include <math.h>

// One thread per (batch, anchor). A % 256 == 0 so each block is within one batch.
// Boxes (N=64) staged in LDS with precomputed corners/areas/xywh + labels.

__global__ __launch_bounds__(256) void anchors_kernel(
    const int*   __restrict__ labels,   // [B, N]
    const float* __restrict__ boxes,    // [B, N, 4] x1,y1,x2,y2
    float*       __restrict__ out,      // [B*A] cls(float) then [B*A*4] loc
    int B, int N, int A, int S)
{
    __shared__ float s_bx1[64], s_by1[64], s_bx2[64], s_by2[64], s_area[64];
    __shared__ float s_cx[64], s_cy[64], s_w[64], s_h[64];
    __shared__ int   s_lab[64];

    const int gid = blockIdx.x * 256 + threadIdx.x;
    const int total = B * A;
    const int b = gid / A;          // constant within a block (A % 256 == 0)
    const int a = gid - b * A;

    const int t = threadIdx.x;
    if (t < N && b < B) {
        float x1 = boxes[(size_t)(b * N + t) * 4 + 0];
        float y1 = boxes[(size_t)(b * N + t) * 4 + 1];
        float x2 = boxes[(size_t)(b * N + t) * 4 + 2];
        float y2 = boxes[(size_t)(b * N + t) * 4 + 3];
        // boxes_xywh exactly as reference: cx=(x1+x2)/2, w=x2-x1+1
        float cx = (x1 + x2) * 0.5f;
        float cy = (y1 + y2) * 0.5f;
        float w  = x2 - x1 + 1.0f;
        float h  = y2 - y1 + 1.0f;
        // corners re-derived from xywh exactly as reference does
        float bx1 = cx - w * 0.5f;
        float by1 = cy - h * 0.5f;
        float bx2 = cx + w * 0.5f;
        float by2 = cy + h * 0.5f;
        s_bx1[t] = bx1; s_by1[t] = by1; s_bx2[t] = bx2; s_by2[t] = by2;
        s_area[t] = (bx2 - bx1 + 1.0f) * (by2 - by1 + 1.0f);
        s_cx[t] = cx; s_cy[t] = cy; s_w[t] = w; s_h[t] = h;
        s_lab[t] = labels[b * N + t];
    }
    __syncthreads();
    if (gid >= total) return;

    // ---- decode anchor index a -> (level, cell_y, cell_x, anchor k) ----
    int r = a;
    int lvl = 0, fm = 0;
    for (int i = 0; i < 4; ++i) {
        int f = (S + (1 << (i + 2)) - 1) >> (i + 2);
        int cnt = f * f * 9;
        if (r < cnt) { lvl = i; fm = f; break; }
        r -= cnt;
    }
    const int k    = r % 9;
    const int cell = r / 9;
    const int cj   = cell % fm;   // x (gx = centers[col])
    const int ci   = cell / fm;   // y (gy = centers[row])

    // anchor w/h in double to bit-match numpy float32 cast of python double math.
    // ANCHOR_AREAS = {4^2, 16^2, 64^2, 128^2} = 2^{4, 8, 12, 14}  (NOT uniform!)
    const int area_shift = (lvl == 3) ? 14 : (4 + 4 * lvl);
    const double s_area_d = (double)(1 << area_shift);
    const int    ar_i = k / 3, sr_i = k - ar_i * 3;
    const double ar = (ar_i == 0) ? 0.5 : (ar_i == 1 ? 1.0 : 2.0);
    const double sr = (sr_i == 0) ? 1.0 : (sr_i == 1 ? 2.0 : 0.75);
    const double hd = sqrt(s_area_d / ar);
    const double wd = ar * hd;
    const float aw = (float)(wd * sr);
    const float ah = (float)(hd * sr);

    const float grid = (float)S / (float)fm;                         // 4,8,16,32 exact
    const float acx = ((float)cj + 0.5f) * grid;
    const float acy = ((float)ci + 0.5f) * grid;

    const float ax1 = acx - aw * 0.5f;
    const float ay1 = acy - ah * 0.5f;
    const float ax2 = acx + aw * 0.5f;
    const float ay2 = acy + ah * 0.5f;
    const float area_a = (ax2 - ax1 + 1.0f) * (ay2 - ay1 + 1.0f);

    // ---- argmax IoU over N boxes (first-occurrence on ties, like jnp.argmax) ----
    float best = -1.0f;
    int   bj   = 0;
    for (int j = 0; j < N; ++j) {
        float ltx = fmaxf(ax1, s_bx1[j]);
        float lty = fmaxf(ay1, s_by1[j]);
        float rbx = fminf(ax2, s_bx2[j]);
        float rby = fminf(ay2, s_by2[j]);
        float iw  = fmaxf(rbx - ltx + 1.0f, 0.0f);
        float ih  = fmaxf(rby - lty + 1.0f, 0.0f);
        float inter = iw * ih;
        float iou = inter / (area_a + s_area[j] - inter);
        if (iou > best) { best = iou; bj = j; }
    }

    // ---- class target (replicates the two jnp.where in order) ----
    int cls = s_lab[bj];
    if (best < 0.5f) cls = 0;
    if (best > 0.4f && best < 0.5f) cls = -1;
    out[(size_t)b * A + a] = (float)cls;

    // ---- loc target ----
    const float mcx = s_cx[bj], mcy = s_cy[bj], mw = s_w[bj], mh = s_h[bj];
    float4 loc;
    loc.x = (mcx - acx) / aw;
    loc.y = (mcy - acy) / ah;
    loc.z = logf(mw / aw);
    loc.w = logf(mh / ah);
    reinterpret_cast<float4*>(out + (size_t)B * A)[gid] = loc;
}

extern "C" void kernel_launch(void* const* d_in, const int* in_sizes, int n_in,
                              void* d_out, int out_size, void* d_ws, size_t ws_size,
                              hipStream_t stream) {
    const int S = 512;  // setup_inputs() fixed input_size
    int A = 0;
    for (int i = 0; i < 4; ++i) {
        int f = (S + (1 << (i + 2)) - 1) >> (i + 2);
        A += f * f * 9;
    }
    const int B = out_size / (5 * A);       // out = B*A cls + B*A*4 loc
    const int N = in_sizes[0] / B;          // labels is [B, N]

    const int total  = B * A;
    const int blocks = (total + 255) / 256;

    anchors_kernel<<<blocks, 256, 0, stream>>>(
        (const int*)d_in[0], (const float*)d_in[1], (float*)d_out, B, N, A, S);
}

// Round 5
// 34.297 us; speedup vs baseline: 1.3590x; 1.3590x over previous
//
#include <hip/hip_runtime.h>
#include <math.h>

// One thread per (batch, anchor). A % 256 == 0 so each block is within one batch.
// Division-free argmax (cross-multiplied compare); exact IEEE div only for the
// winning IoU so the 0.4/0.5 threshold logic sees a bit-identical value.

__global__ __launch_bounds__(256) void anchors_kernel(
    const int*   __restrict__ labels,   // [B, N]
    const float* __restrict__ boxes,    // [B, N, 4] x1,y1,x2,y2
    float*       __restrict__ out,      // [B*A] cls(float) then [B*A*4] loc
    int B, int N, int A, int S)
{
    __shared__ float4 s_corn[64];   // bx1, by1, bx2, by2
    __shared__ float  s_area[64];
    __shared__ float4 s_xywh[64];   // cx, cy, w, h
    __shared__ int    s_lab[64];

    const int gid = blockIdx.x * 256 + threadIdx.x;
    const int b = gid / A;          // constant within a block (A % 256 == 0)
    const int a = gid - b * A;
    const int t = threadIdx.x;

    if (t < N && b < B) {
        float4 bx = reinterpret_cast<const float4*>(boxes)[b * N + t];
        float cx = (bx.x + bx.z) * 0.5f;
        float cy = (bx.y + bx.w) * 0.5f;
        float w  = bx.z - bx.x + 1.0f;
        float h  = bx.w - bx.y + 1.0f;
        float bx1 = cx - w * 0.5f;
        float by1 = cy - h * 0.5f;
        float bx2 = cx + w * 0.5f;
        float by2 = cy + h * 0.5f;
        s_corn[t] = make_float4(bx1, by1, bx2, by2);
        s_area[t] = (bx2 - bx1 + 1.0f) * (by2 - by1 + 1.0f);
        s_xywh[t] = make_float4(cx, cy, w, h);
        s_lab[t]  = labels[b * N + t];
    }
    __syncthreads();
    if (gid >= B * A) return;

    // ---- decode anchor index a -> (level, cell, k) ----
    int r = a;
    int lvl = 0;
    int fm  = (S + 3) >> 2;
    #pragma unroll
    for (int i = 0; i < 3; ++i) {
        int cnt = fm * fm * 9;
        if (r >= cnt) { r -= cnt; lvl = i + 1; fm = (S + (1 << (i + 3)) - 1) >> (i + 3); }
    }
    const int k    = r % 9;
    const int cell = r / 9;
    const int lfm  = 31 - __clz(fm);      // fm is pow2 for S=512
    const int cj   = cell & (fm - 1);     // x
    const int ci   = cell >> lfm;         // y

    // ---- anchor w/h, bit-exact vs numpy double math ----
    // areas {16,256,4096,16384} = (2^{2,4,6,7})^2; sqrt(area/ar) = 2^s * {sqrt2, 1, sqrt2/2}
    // (pow2 scalings commute with rounding -> identical to sqrt(area/ar) in double)
    const int ar_i = (k >= 6) ? 2 : ((k >= 3) ? 1 : 0);
    const int sr_i = k - 3 * ar_i;
    const double s2  = sqrt(2.0);                                   // constant-folded
    const double hb  = (ar_i == 0) ? s2 : (ar_i == 1 ? 1.0 : 0.5 * s2);
    const double wb  = (ar_i == 0) ? 0.5 * s2 : (ar_i == 1 ? 1.0 : s2);
    const double srd = (sr_i == 0) ? 1.0 : (sr_i == 1 ? 2.0 : 0.75);
    const float  sl  = (float)(1 << ((lvl == 3) ? 7 : (2 + 2 * lvl))); // 4,16,64,128
    const float  aw  = (float)(wb * srd) * sl;
    const float  ah  = (float)(hb * srd) * sl;

    const float grid = (float)S / (float)fm;          // 4,8,16,32 exact
    const float acx = ((float)cj + 0.5f) * grid;
    const float acy = ((float)ci + 0.5f) * grid;

    const float ax1 = acx - aw * 0.5f;
    const float ay1 = acy - ah * 0.5f;
    const float ax2 = acx + aw * 0.5f;
    const float ay2 = acy + ah * 0.5f;
    const float area_a = (ax2 - ax1 + 1.0f) * (ay2 - ay1 + 1.0f);

    // ---- argmax IoU over N boxes, division-free compare ----
    float best_in, best_un;
    int   bj = 0;
    {
        float4 c0 = s_corn[0];
        float iw = fmaxf(fminf(ax2, c0.z) - fmaxf(ax1, c0.x) + 1.0f, 0.0f);
        float ih = fmaxf(fminf(ay2, c0.w) - fmaxf(ay1, c0.y) + 1.0f, 0.0f);
        best_in = iw * ih;
        best_un = (area_a + s_area[0]) - best_in;
    }
    #pragma unroll 8
    for (int j = 1; j < N; ++j) {
        float4 c = s_corn[j];
        float iw = fmaxf(fminf(ax2, c.z) - fmaxf(ax1, c.x) + 1.0f, 0.0f);
        float ih = fmaxf(fminf(ay2, c.w) - fmaxf(ay1, c.y) + 1.0f, 0.0f);
        float in_ = iw * ih;
        float un_ = (area_a + s_area[j]) - in_;
        bool better = (in_ * best_un) > (best_in * un_);
        best_in = better ? in_ : best_in;
        best_un = better ? un_ : best_un;
        bj      = better ? j   : bj;
    }
    const float best = best_in / best_un;   // exact IEEE, same operands as reference

    // ---- class target (replicates the two jnp.where in order) ----
    int cls = s_lab[bj];
    if (best < 0.5f) cls = 0;
    if (best > 0.4f && best < 0.5f) cls = -1;
    out[(size_t)b * A + a] = (float)cls;

    // ---- loc target ----
    float4 m = s_xywh[bj];
    float4 loc;
    loc.x = (m.x - acx) / aw;
    loc.y = (m.y - acy) / ah;
    loc.z = logf(m.z / aw);
    loc.w = logf(m.w / ah);
    reinterpret_cast<float4*>(out + (size_t)B * A)[gid] = loc;
}

extern "C" void kernel_launch(void* const* d_in, const int* in_sizes, int n_in,
                              void* d_out, int out_size, void* d_ws, size_t ws_size,
                              hipStream_t stream) {
    const int S = 512;  // setup_inputs() fixed input_size
    int A = 0;
    for (int i = 0; i < 4; ++i) {
        int f = (S + (1 << (i + 2)) - 1) >> (i + 2);
        A += f * f * 9;
    }
    const int B = out_size / (5 * A);       // out = B*A cls + B*A*4 loc
    const int N = in_sizes[0] / B;          // labels is [B, N]

    const int total  = B * A;
    const int blocks = (total + 255) / 256;

    anchors_kernel<<<blocks, 256, 0, stream>>>(
        (const int*)d_in[0], (const float*)d_in[1], (float*)d_out, B, N, A, S);
}

// Round 6
// 18.233 us; speedup vs baseline: 2.5564x; 1.8810x over previous
//
#include <hip/hip_runtime.h>
#include <math.h>

// One thread per (batch, anchor). Each 256-thread block lies in one batch AND
// one pyramid level (level anchor counts are all multiples of 256 at S=512).
// Wave 0 prunes the 64 boxes against the block's analytic anchor bbox: pruned
// boxes have IoU exactly 0 for every anchor in the block, so the argmax is
// unchanged (all-zero rows fall back to box 0, matching jnp.argmax).
// Hot-path IoU math is bit-identical to the previously verified kernel.

__global__ __launch_bounds__(256) void anchors_kernel(
    const int*   __restrict__ labels,   // [B, N]
    const float* __restrict__ boxes,    // [B, N, 4] x1,y1,x2,y2
    float*       __restrict__ out,      // [B*A] cls(float) then [B*A*4] loc
    int B, int N, int A, int S)
{
    __shared__ float4 s_corn[64];   // compacted: bx1, by1, bx2, by2
    __shared__ float  s_area[64];   // compacted
    __shared__ float4 s_xywh[64];   // compacted: cx, cy, w, h
    __shared__ int    s_lab[64];    // compacted
    __shared__ float4 s_box0;       // original box 0 xywh (fallback)
    __shared__ int    s_lab0;
    __shared__ int    s_Lb;

    const int gid = blockIdx.x * 256 + threadIdx.x;
    const int b = gid / A;          // constant within block (A % 256 == 0)
    const int t = threadIdx.x;

    // ---- block-uniform: level decode for first anchor of block ----
    const int a0 = blockIdx.x * 256 - b * A;
    int r0 = a0;
    int lvl = 0;
    int fm  = S >> 2;               // 128, 64, 32, 16 (S=512 -> ceil is exact)
    #pragma unroll
    for (int i = 0; i < 3; ++i) {
        int cnt = fm * fm * 9;
        if (r0 >= cnt) { r0 -= cnt; lvl = i + 1; fm >>= 1; }
    }
    const int lfm = 31 - __clz(fm);
    const float grid = (float)(4 << lvl);                       // 4,8,16,32
    const float sl   = (float)((lvl == 3) ? 128 : (4 << (2 * lvl))); // 4,16,64,128

    // ---- block anchor bbox (uniform) ----
    const int cell_lo = r0 / 9;
    const int cell_hi = (r0 + 255) / 9;
    const int ci_lo = cell_lo >> lfm, ci_hi = cell_hi >> lfm;
    int cj_lo, cj_hi;
    if (ci_lo == ci_hi) { cj_lo = cell_lo & (fm - 1); cj_hi = cell_hi & (fm - 1); }
    else                { cj_lo = 0;                  cj_hi = fm - 1; }
    const float ext = 1.41422f * sl + 0.5f;   // max anchor half-extent + slack
    const float bbx1 = ((float)cj_lo + 0.5f) * grid - ext;
    const float bbx2 = ((float)cj_hi + 0.5f) * grid + ext;
    const float bby1 = ((float)ci_lo + 0.5f) * grid - ext;
    const float bby2 = ((float)ci_hi + 0.5f) * grid + ext;

    // ---- wave 0: load boxes, prune vs bbox, order-preserving compaction ----
    if (t < 64) {
        bool pred = false;
        float cx = 0, cy = 0, w = 0, h = 0, bx1 = 0, by1 = 0, bx2 = 0, by2 = 0;
        int lab = 0;
        if (t < N && b < B) {
            float4 bx = reinterpret_cast<const float4*>(boxes)[b * N + t];
            cx = (bx.x + bx.z) * 0.5f;
            cy = (bx.y + bx.w) * 0.5f;
            w  = bx.z - bx.x + 1.0f;
            h  = bx.w - bx.y + 1.0f;
            bx1 = cx - w * 0.5f;
            by1 = cy - h * 0.5f;
            bx2 = cx + w * 0.5f;
            by2 = cy + h * 0.5f;
            lab = labels[b * N + t];
            pred = (fminf(bbx2, bx2) - fmaxf(bbx1, bx1) + 1.0f > 0.0f) &&
                   (fminf(bby2, by2) - fmaxf(bby1, by1) + 1.0f > 0.0f);
        }
        unsigned long long mask = __ballot(pred);
        if (pred) {
            int pos = __popcll(mask & ((1ull << t) - 1ull));
            s_corn[pos] = make_float4(bx1, by1, bx2, by2);
            s_area[pos] = (bx2 - bx1 + 1.0f) * (by2 - by1 + 1.0f);
            s_xywh[pos] = make_float4(cx, cy, w, h);
            s_lab[pos]  = lab;
        }
        if (t == 0) {
            s_Lb   = __popcll(mask);
            s_box0 = make_float4(cx, cy, w, h);   // lane 0 holds original box 0
            s_lab0 = lab;
        }
    }
    __syncthreads();

    // ---- per-thread anchor ----
    const int r    = r0 + t;
    const int k    = r % 9;
    const int cell = r / 9;
    const int cj   = cell & (fm - 1);
    const int ci   = cell >> lfm;

    // anchor w/h, bit-exact vs numpy double math (pow2 scalings commute w/ rounding)
    const int ar_i = (k >= 6) ? 2 : ((k >= 3) ? 1 : 0);
    const int sr_i = k - 3 * ar_i;
    const double s2  = sqrt(2.0);                                  // folded
    const double hb  = (ar_i == 0) ? s2 : (ar_i == 1 ? 1.0 : 0.5 * s2);
    const double wb  = (ar_i == 0) ? 0.5 * s2 : (ar_i == 1 ? 1.0 : s2);
    const double srd = (sr_i == 0) ? 1.0 : (sr_i == 1 ? 2.0 : 0.75);
    const float  aw  = (float)(wb * srd) * sl;
    const float  ah  = (float)(hb * srd) * sl;

    const float acx = ((float)cj + 0.5f) * grid;
    const float acy = ((float)ci + 0.5f) * grid;
    const float ax1 = acx - aw * 0.5f;
    const float ay1 = acy - ah * 0.5f;
    const float ax2 = acx + aw * 0.5f;
    const float ay2 = acy + ah * 0.5f;
    const float area_a = (ax2 - ax1 + 1.0f) * (ay2 - ay1 + 1.0f);

    // ---- argmax IoU over compacted list, division-free compare ----
    float best_in = 0.0f, best_un = 1.0f;
    int   bj = -1;
    const int L = s_Lb;
    for (int j = 0; j < L; ++j) {
        float4 c = s_corn[j];
        float iw = fmaxf(fminf(ax2, c.z) - fmaxf(ax1, c.x) + 1.0f, 0.0f);
        float ih = fmaxf(fminf(ay2, c.w) - fmaxf(ay1, c.y) + 1.0f, 0.0f);
        float in_ = iw * ih;
        float un_ = (area_a + s_area[j]) - in_;
        bool better = (in_ * best_un) > (best_in * un_);
        best_in = better ? in_ : best_in;
        best_un = better ? un_ : best_un;
        bj      = better ? j   : bj;
    }

    if (gid >= B * A) return;

    float best, mcx, mcy, mw, mh;
    int lab;
    if (bj >= 0) {
        best = best_in / best_un;   // exact IEEE, same operands as reference
        float4 m = s_xywh[bj];
        mcx = m.x; mcy = m.y; mw = m.z; mh = m.w;
        lab = s_lab[bj];
    } else {
        best = 0.0f;                // all IoUs zero -> argmax = 0 (box 0)
        float4 m = s_box0;
        mcx = m.x; mcy = m.y; mw = m.z; mh = m.w;
        lab = s_lab0;
    }

    int cls = lab;
    if (best < 0.5f) cls = 0;
    if (best > 0.4f && best < 0.5f) cls = -1;
    out[(size_t)gid] = (float)cls;

    float4 loc;
    loc.x = (mcx - acx) / aw;
    loc.y = (mcy - acy) / ah;
    loc.z = __logf(mw / aw);
    loc.w = __logf(mh / ah);
    reinterpret_cast<float4*>(out + (size_t)B * A)[gid] = loc;
}

extern "C" void kernel_launch(void* const* d_in, const int* in_sizes, int n_in,
                              void* d_out, int out_size, void* d_ws, size_t ws_size,
                              hipStream_t stream) {
    const int S = 512;  // setup_inputs() fixed input_size
    int A = 0;
    for (int i = 0; i < 4; ++i) {
        int f = (S + (1 << (i + 2)) - 1) >> (i + 2);
        A += f * f * 9;
    }
    const int B = out_size / (5 * A);       // out = B*A cls + B*A*4 loc
    const int N = in_sizes[0] / B;          // labels is [B, N]

    const int total  = B * A;
    const int blocks = (total + 255) / 256;

    anchors_kernel<<<blocks, 256, 0, stream>>>(
        (const int*)d_in[0], (const float*)d_in[1], (float*)d_out, B, N, A, S);
}

// Round 7
// 17.341 us; speedup vs baseline: 2.6880x; 1.0514x over previous
//
#include <hip/hip_runtime.h>
#include <math.h>

// One thread per (batch, anchor). Each 256-thread block lies in one batch AND
// one pyramid level (level anchor counts are multiples of 256 at S=512).
// Per-WAVE pruning: each wave's 64 anchors span ~7 grid cells; boxes whose
// rectangle misses the wave's analytic anchor bbox have IoU exactly 0 for every
// anchor in the wave, so dropping them cannot change any argmax (all-zero rows
// fall back to box 0 = jnp.argmax of zeros). Compaction is wave-local ->
// no __syncthreads needed. Hot-path IoU math bit-identical to verified kernel.

__global__ __launch_bounds__(256) void anchors_kernel(
    const int*   __restrict__ labels,   // [B, N]
    const float* __restrict__ boxes,    // [B, N, 4] x1,y1,x2,y2
    float*       __restrict__ out,      // [B*A] cls(float) then [B*A*4] loc
    int B, int N, int A, int S)
{
    __shared__ float4 s_corn[256];   // per-wave segments of 64
    __shared__ float  s_area[256];
    __shared__ float4 s_xywh[256];
    __shared__ int    s_lab[256];
    __shared__ float4 s_b0[4];       // per-wave original box 0 xywh (fallback)
    __shared__ int    s_l0[4];

    const int t    = threadIdx.x;
    const int lane = t & 63;
    const int wid  = t >> 6;
    const int gid  = blockIdx.x * 256 + t;

    // ---- block-uniform batch + level decode ----
    const int b  = (blockIdx.x * 256) / A;       // A % 256 == 0
    int r0 = blockIdx.x * 256 - b * A;
    int lvl = 0, fm = S >> 2;                    // 128,64,32,16 (exact for S=512)
    #pragma unroll
    for (int i = 0; i < 3; ++i) {
        int cnt = fm * fm * 9;
        if (r0 >= cnt) { r0 -= cnt; lvl = i + 1; fm >>= 1; }
    }
    const int   lfm  = 31 - __clz(fm);
    const float grid = (float)(4 << lvl);                            // 4,8,16,32
    const float sl   = (float)((lvl == 3) ? 128 : (4 << (2 * lvl))); // 4,16,64,128

    // ---- wave anchor bbox (uniform within wave) ----
    const int wr0     = r0 + wid * 64;
    const int cell_lo = wr0 / 9;
    const int cell_hi = (wr0 + 63) / 9;
    const int ci_lo = cell_lo >> lfm, ci_hi = cell_hi >> lfm;
    int cj_lo, cj_hi;
    if (ci_lo == ci_hi) { cj_lo = cell_lo & (fm - 1); cj_hi = cell_hi & (fm - 1); }
    else                { cj_lo = 0;                  cj_hi = fm - 1; }
    const float ext  = 1.41422f * sl + 0.5f;   // max half-extent + IoU +1 slack
    const float bbx1 = ((float)cj_lo + 0.5f) * grid - ext;
    const float bbx2 = ((float)cj_hi + 0.5f) * grid + ext;
    const float bby1 = ((float)ci_lo + 0.5f) * grid - ext;
    const float bby2 = ((float)ci_hi + 0.5f) * grid + ext;

    // ---- per-wave: load box[lane], prune, order-preserving compaction ----
    int L;
    {
        bool  pred = false;
        float cx = 0, cy = 0, w = 0, h = 0, bx1 = 0, by1 = 0, bx2 = 0, by2 = 0;
        int   lab = 0;
        if (lane < N) {
            float4 bx = reinterpret_cast<const float4*>(boxes)[b * N + lane];
            cx = (bx.x + bx.z) * 0.5f;
            cy = (bx.y + bx.w) * 0.5f;
            w  = bx.z - bx.x + 1.0f;
            h  = bx.w - bx.y + 1.0f;
            bx1 = cx - w * 0.5f;  by1 = cy - h * 0.5f;
            bx2 = cx + w * 0.5f;  by2 = cy + h * 0.5f;
            lab = labels[b * N + lane];
            pred = (fminf(bbx2, bx2) - fmaxf(bbx1, bx1) + 1.0f > 0.0f) &&
                   (fminf(bby2, by2) - fmaxf(bby1, by1) + 1.0f > 0.0f);
        }
        unsigned long long mask = __ballot(pred);
        if (pred) {
            int pos = wid * 64 + __popcll(mask & ((1ull << lane) - 1ull));
            s_corn[pos] = make_float4(bx1, by1, bx2, by2);
            s_area[pos] = (bx2 - bx1 + 1.0f) * (by2 - by1 + 1.0f);
            s_xywh[pos] = make_float4(cx, cy, w, h);
            s_lab[pos]  = lab;
        }
        if (lane == 0) { s_b0[wid] = make_float4(cx, cy, w, h); s_l0[wid] = lab; }
        L = __popcll(mask);
    }
    // wave-local LDS exchange: in-order DS pipe + compiler lgkmcnt, no barrier.

    // ---- per-thread anchor ----
    const int r    = r0 + t;
    const int k    = r % 9;
    const int cell = r / 9;
    const int cj   = cell & (fm - 1);
    const int ci   = cell >> lfm;

    // anchor w/h, bit-exact vs numpy double math (pow2 scalings commute w/ rounding)
    const int ar_i = (k >= 6) ? 2 : ((k >= 3) ? 1 : 0);
    const int sr_i = k - 3 * ar_i;
    const double s2  = sqrt(2.0);                                  // folded
    const double hb  = (ar_i == 0) ? s2 : (ar_i == 1 ? 1.0 : 0.5 * s2);
    const double wb  = (ar_i == 0) ? 0.5 * s2 : (ar_i == 1 ? 1.0 : s2);
    const double srd = (sr_i == 0) ? 1.0 : (sr_i == 1 ? 2.0 : 0.75);
    const float  aw  = (float)(wb * srd) * sl;
    const float  ah  = (float)(hb * srd) * sl;

    const float acx = ((float)cj + 0.5f) * grid;
    const float acy = ((float)ci + 0.5f) * grid;
    const float ax1 = acx - aw * 0.5f;
    const float ay1 = acy - ah * 0.5f;
    const float ax2 = acx + aw * 0.5f;
    const float ay2 = acy + ah * 0.5f;
    const float area_a = (ax2 - ax1 + 1.0f) * (ay2 - ay1 + 1.0f);

    // ---- argmax IoU over this wave's compacted list, division-free compare ----
    float best_in = 0.0f, best_un = 1.0f;
    int   bj = -1;
    const int base = wid * 64;
    for (int j = 0; j < L; ++j) {
        float4 c = s_corn[base + j];
        float iw = fmaxf(fminf(ax2, c.z) - fmaxf(ax1, c.x) + 1.0f, 0.0f);
        float ih = fmaxf(fminf(ay2, c.w) - fmaxf(ay1, c.y) + 1.0f, 0.0f);
        float in_ = iw * ih;
        float un_ = (area_a + s_area[base + j]) - in_;
        bool better = (in_ * best_un) > (best_in * un_);
        best_in = better ? in_ : best_in;
        best_un = better ? un_ : best_un;
        bj      = better ? j   : bj;
    }

    float best, mcx, mcy, mw, mh;
    int lab;
    if (bj >= 0) {
        best = best_in / best_un;   // exact IEEE, same operands as reference
        float4 m = s_xywh[base + bj];
        mcx = m.x; mcy = m.y; mw = m.z; mh = m.w;
        lab = s_lab[base + bj];
    } else {
        best = 0.0f;                // all IoUs zero -> argmax = 0 (box 0)
        float4 m = s_b0[wid];
        mcx = m.x; mcy = m.y; mw = m.z; mh = m.w;
        lab = s_l0[wid];
    }

    int cls = lab;
    if (best < 0.5f) cls = 0;
    if (best > 0.4f && best < 0.5f) cls = -1;

    // v_rcp_f32 (~1 ulp) for loc divides: |err| <= ~3e-5 absolute, tolerance 7.8e-3
    const float rcp_aw = __builtin_amdgcn_rcpf(aw);
    const float rcp_ah = __builtin_amdgcn_rcpf(ah);
    float4 loc;
    loc.x = (mcx - acx) * rcp_aw;
    loc.y = (mcy - acy) * rcp_ah;
    loc.z = __logf(mw * rcp_aw);
    loc.w = __logf(mh * rcp_ah);

    if (gid < B * A) {
        out[(size_t)gid] = (float)cls;
        reinterpret_cast<float4*>(out + (size_t)B * A)[gid] = loc;
    }
}

extern "C" void kernel_launch(void* const* d_in, const int* in_sizes, int n_in,
                              void* d_out, int out_size, void* d_ws, size_t ws_size,
                              hipStream_t stream) {
    const int S = 512;  // setup_inputs() fixed input_size
    int A = 0;
    for (int i = 0; i < 4; ++i) {
        int f = (S + (1 << (i + 2)) - 1) >> (i + 2);
        A += f * f * 9;
    }
    const int B = out_size / (5 * A);       // out = B*A cls + B*A*4 loc
    const int N = in_sizes[0] / B;          // labels is [B, N]

    const int total  = B * A;
    const int blocks = (total + 255) / 256;

    anchors_kernel<<<blocks, 256, 0, stream>>>(
        (const int*)d_in[0], (const float*)d_in[1], (float*)d_out, B, N, A, S);
}